// Round 11
// baseline (171.650 us; speedup 1.0000x reference)
//
#include <hip/hip_runtime.h>
#include <math.h>

// Problem constants (reference: B=2, S=T=400, D=512)
#define BB 2
#define SS 400
#define DD 512
#define TWO_LOG2E 2.8853900817779268f

#if __has_builtin(__builtin_amdgcn_exp2f)
#define EXP2F(x) __builtin_amdgcn_exp2f(x)
#else
#define EXP2F(x) exp2f(x)
#endif
#define RCPF(x) __builtin_amdgcn_rcpf(x)

// Workspace float layout (peak 8.65 MB):
//   Ea   [0,       409600) : exp2(2L*(input@Wq + bq))            [B,T,D]
//   M    [409600,  819200) : mb@Wout_top                         [B,S,D]
//   Eb4  [819200, 1228800) : exp2(2L*(mb@Wc)), packed [B][D/4][S][4]
//   X    [1228800, ...)    : bf16 staging (shorts):
//        wt  [0,        1048576) : Wt [g][1024][512]
//        ahi [1048576,  1458176) : hi(A) [g][800][512]
//        alo [1458176,  1867776) : lo(A) [g][800][512]
// out0 gets input@Wout_bot + bout from k1 (g0 cols>=512); k23 adds align@M.
#define EAOFF 0
#define MOFF 409600
#define EB4OFF 819200
#define XOFF 1228800

typedef __bf16 bf16x8 __attribute__((ext_vector_type(8)));
typedef float floatx16 __attribute__((ext_vector_type(16)));

// ---------------------------------------------------------------------------
// K0: fused prep. Flat grid 1824 blocks, 256 thr.
//  gid < 1024: Wt[g][n][k] bf16 transpose-pack (32x32 LDS tiles).
//   g0: n<512 -> Wq[k][n]; n>=512 -> Wout[512+k][n-512]  (bot half)
//   g1: n<512 -> Wc[k][n]; n>=512 -> Wout[k][n-512]      (top half)
//  gid >= 1024: two-term bf16 split of A (input / mb): ahi=bf16(a),
//   alo=bf16(a-ahi); float4 per thread.
// ---------------------------------------------------------------------------
__global__ __launch_bounds__(256) void k0_all(
    const float* __restrict__ Wq, const float* __restrict__ Wc,
    const float* __restrict__ Wout, const float* __restrict__ input,
    const float* __restrict__ mbk, unsigned short* __restrict__ wt,
    unsigned short* __restrict__ ahi, unsigned short* __restrict__ alo)
{
    const int gid = blockIdx.x;
    if (gid < 1024) {
        const int g   = gid >> 9;
        const int rem = gid & 511;
        const int k0  = (rem & 15) * 32;
        const int n0  = (rem >> 4) * 32;

        __shared__ float tile[32][33];
        const int nn  = threadIdx.x & 31;
        const int kk0 = threadIdx.x >> 5;
        const int n   = n0 + nn;

        #pragma unroll
        for (int p = 0; p < 4; ++p) {
            const int k = k0 + kk0 + p * 8;
            float val;
            if (n0 < 512) val = (g ? Wc : Wq)[(size_t)k * 512 + n];
            else          val = Wout[((size_t)(g ? k : 512 + k)) * 512 + (n - 512)];
            tile[kk0 + p * 8][nn] = val;
        }
        __syncthreads();

        const int kc = threadIdx.x & 31;
        #pragma unroll
        for (int p = 0; p < 4; ++p) {
            const int nl = (threadIdx.x >> 5) + p * 8;
            const __bf16 h = (__bf16)tile[kc][nl];
            wt[((size_t)(g * 1024 + n0 + nl)) * 512 + k0 + kc] =
                __builtin_bit_cast(unsigned short, h);
        }
    } else {
        const int cid = gid - 1024;             // 0..799
        const int g   = (cid >= 400) ? 1 : 0;
        const int i4  = (cid - g * 400) * 256 + threadIdx.x;   // 0..102399
        const float4 a = ((const float4*)(g ? mbk : input))[i4];
        ushort4 h, l;
        #pragma unroll
        for (int j = 0; j < 4; ++j) {
            const float av = (&a.x)[j];
            const __bf16 hh = (__bf16)av;
            (&h.x)[j] = __builtin_bit_cast(unsigned short, hh);
            const __bf16 ll = (__bf16)(av - (float)hh);
            (&l.x)[j] = __builtin_bit_cast(unsigned short, ll);
        }
        ((ushort4*)(ahi + (size_t)g * 409600))[i4] = h;
        ((ushort4*)(alo + (size_t)g * 409600))[i4] = l;
    }
}

// ---------------------------------------------------------------------------
// K1: two merged GEMMs (800 x 1024 x 512) via MFMA, pre-split bf16 A.
// Grid (25 mtiles, 16 npairs, 2 g), 64 thr = 1 wave; wave tile 32x64.
// Inner loop: 4x 16B loads + 4 MFMA, zero VALU.
// C/D: col=lane&31, row=(reg&3)+8*(reg>>2)+4*(lane>>5).
// Fused epilogues by n-range/g: Ea, out0(=P+bout), Eb4 scatter, M.
// ---------------------------------------------------------------------------
__global__ __launch_bounds__(64) void k1_mfma(
    const unsigned short* __restrict__ ahi, const unsigned short* __restrict__ alo,
    const unsigned short* __restrict__ wt, const float* __restrict__ bq,
    const float* __restrict__ bout, float* __restrict__ ws,
    float* __restrict__ out0)
{
    const int lane = threadIdx.x;
    const int mt   = blockIdx.x;          // 0..24
    const int np   = blockIdx.y;          // 0..15
    const int g    = blockIdx.z;
    const int m    = lane & 31;
    const int kh   = lane >> 5;
    const int n0   = np * 64;

    const size_t arow = ((size_t)g * 800 + mt * 32 + m) * 512 + kh * 8;
    const unsigned short* __restrict__ ah = ahi + arow;
    const unsigned short* __restrict__ al = alo + arow;
    const unsigned short* __restrict__ w0 =
        wt + ((size_t)(g * 1024 + n0 + m)) * 512 + kh * 8;
    const unsigned short* __restrict__ w1 = w0 + (size_t)32 * 512;

    floatx16 acc0h, acc0l, acc1h, acc1l;
    #pragma unroll
    for (int i = 0; i < 16; ++i) { acc0h[i] = 0.f; acc0l[i] = 0.f;
                                   acc1h[i] = 0.f; acc1l[i] = 0.f; }

    #pragma unroll 4
    for (int ks = 0; ks < 32; ++ks) {
        const bf16x8 va0 = *(const bf16x8*)(ah + ks * 16);
        const bf16x8 va1 = *(const bf16x8*)(al + ks * 16);
        const bf16x8 bh0 = *(const bf16x8*)(w0 + ks * 16);
        const bf16x8 bh1 = *(const bf16x8*)(w1 + ks * 16);

        acc0h = __builtin_amdgcn_mfma_f32_32x32x16_bf16(va0, bh0, acc0h, 0, 0, 0);
        acc0l = __builtin_amdgcn_mfma_f32_32x32x16_bf16(va1, bh0, acc0l, 0, 0, 0);
        acc1h = __builtin_amdgcn_mfma_f32_32x32x16_bf16(va0, bh1, acc1h, 0, 0, 0);
        acc1l = __builtin_amdgcn_mfma_f32_32x32x16_bf16(va1, bh1, acc1l, 0, 0, 0);
    }

    const floatx16 c0 = acc0h + acc0l;
    const floatx16 c1 = acc1h + acc1l;
    const int rbase = kh * 4;

    #pragma unroll
    for (int r = 0; r < 16; ++r) {
        const int row  = (r & 3) + 8 * (r >> 2) + rbase;   // 0..31
        const int grow = mt * 32 + row;                    // 0..799
        const int bi   = (grow >= SS) ? 1 : 0;
        const int rl   = grow - bi * SS;                   // t or s local
        #pragma unroll
        for (int u = 0; u < 2; ++u) {
            const float val  = u ? c1[r] : c0[r];
            const int   gcol = n0 + u * 32 + m;
            if (g == 0) {
                if (gcol < 512) {
                    ws[EAOFF + (size_t)grow * 512 + gcol] =
                        EXP2F(TWO_LOG2E * (val + bq[gcol]));
                } else {
                    const int d = gcol - 512;
                    out0[((size_t)(rl * BB + bi)) * 512 + d] = val + bout[d];
                }
            } else {
                if (gcol < 512) {
                    ws[EB4OFF + (size_t)((bi * 128 + (gcol >> 2)) * SS + rl) * 4
                       + (gcol & 3)] = EXP2F(TWO_LOG2E * val);
                } else {
                    ws[MOFF + (size_t)grow * 512 + (gcol - 512)] = val;
                }
            }
        }
    }
}

// ---------------------------------------------------------------------------
// K23: fused scores + softmax + context + output. Block = (t-quad, b),
// grid (100,2)=200 blocks, 512 thr (8 waves).
// Phase A (thread=s): score(t,s) = -2 sum_e v_e/(Ea[t][e]*Eb[e][s]+1) for
// 4 t's sharing each Eb load; softmax inline; align -> out1 + LDS.
// Phase B (thread=d): out0[t,b,d] = P + sum_s align_lds[s]*M[b,s,d];
// M read once per 4 t's; align via broadcast ds_read_b128.
// ---------------------------------------------------------------------------
__global__ __launch_bounds__(512) void k23_attn(
    const float* __restrict__ ws, const float* __restrict__ v,
    const int* __restrict__ lens, float* __restrict__ out1,
    float* __restrict__ out0)
{
    const int tq = blockIdx.x;            // 0..99
    const int b  = blockIdx.y;
    const int t0 = tq * 4;
    const int tid = threadIdx.x;
    const int s   = tid;
    const int sidx = (s < SS) ? s : 0;
    const int len  = lens[b];

    __shared__ float lea[4][512];
    __shared__ float lv[512];
    __shared__ float al4[SS][4];
    __shared__ float wred[4][8];

    for (int i = tid; i < 2048; i += 512)
        lea[i >> 9][i & 511] =
            ws[EAOFF + (size_t)(b * SS + t0 + (i >> 9)) * 512 + (i & 511)];
    lv[tid] = v[tid];
    __syncthreads();

    const float4* __restrict__ eb4 =
        (const float4*)(ws + EB4OFF) + (size_t)b * 128 * SS + sidx;

    float acc[4] = {0.f, 0.f, 0.f, 0.f};
    #pragma unroll 4
    for (int e4 = 0; e4 < 128; ++e4) {
        const float4 eb  = eb4[(size_t)e4 * SS];
        const float4 vv  = *(const float4*)&lv[e4 * 4];
        const float4 ea0 = *(const float4*)&lea[0][e4 * 4];
        const float4 ea1 = *(const float4*)&lea[1][e4 * 4];
        const float4 ea2 = *(const float4*)&lea[2][e4 * 4];
        const float4 ea3 = *(const float4*)&lea[3][e4 * 4];
        #pragma unroll
        for (int j = 0; j < 4; ++j) {
            const float ebv = (&eb.x)[j];
            const float vj  = (&vv.x)[j];
            acc[0] = fmaf(vj, RCPF(fmaf((&ea0.x)[j], ebv, 1.f)), acc[0]);
            acc[1] = fmaf(vj, RCPF(fmaf((&ea1.x)[j], ebv, 1.f)), acc[1]);
            acc[2] = fmaf(vj, RCPF(fmaf((&ea2.x)[j], ebv, 1.f)), acc[2]);
            acc[3] = fmaf(vj, RCPF(fmaf((&ea3.x)[j], ebv, 1.f)), acc[3]);
        }
    }

    bool  vmask[4];
    float sc[4];
    #pragma unroll
    for (int t = 0; t < 4; ++t) {
        vmask[t] = (s < SS) && (s < len) && (s != t0 + t);
        sc[t] = vmask[t] ? -2.f * acc[t] : -INFINITY;
    }

    const int wid  = tid >> 6;
    const int lane = tid & 63;

    float mloc[4] = {sc[0], sc[1], sc[2], sc[3]};
    #pragma unroll
    for (int off = 32; off > 0; off >>= 1) {
        #pragma unroll
        for (int t = 0; t < 4; ++t)
            mloc[t] = fmaxf(mloc[t], __shfl_xor(mloc[t], off));
    }
    if (lane == 0) {
        #pragma unroll
        for (int t = 0; t < 4; ++t) wred[t][wid] = mloc[t];
    }
    __syncthreads();
    float mx[4];
    #pragma unroll
    for (int t = 0; t < 4; ++t) {
        float m = wred[t][0];
        #pragma unroll
        for (int w = 1; w < 8; ++w) m = fmaxf(m, wred[t][w]);
        mx[t] = m;
    }
    __syncthreads();

    float p[4], sloc[4];
    #pragma unroll
    for (int t = 0; t < 4; ++t) {
        p[t] = vmask[t] ? __expf(sc[t] - mx[t]) : 0.f;
        sloc[t] = p[t];
    }
    #pragma unroll
    for (int off = 32; off > 0; off >>= 1) {
        #pragma unroll
        for (int t = 0; t < 4; ++t) sloc[t] += __shfl_xor(sloc[t], off);
    }
    if (lane == 0) {
        #pragma unroll
        for (int t = 0; t < 4; ++t) wred[t][wid] = sloc[t];
    }
    __syncthreads();
    #pragma unroll
    for (int t = 0; t < 4; ++t) {
        float tot = wred[t][0];
        #pragma unroll
        for (int w = 1; w < 8; ++w) tot += wred[t][w];
        const float a = p[t] * RCPF(tot);
        if (s < SS) {
            out1[((size_t)((t0 + t) * BB) + b) * SS + s] = a;
            al4[s][t] = a;
        }
    }
    __syncthreads();

    // ---- Phase B: thread = d ----
    const int d = tid;                       // 0..511
    const float* __restrict__ Mb = ws + MOFF + (size_t)b * SS * DD;

    float pv[4], oacc[4];
    #pragma unroll
    for (int t = 0; t < 4; ++t) {
        pv[t]   = out0[((size_t)((t0 + t) * BB) + b) * DD + d];
        oacc[t] = 0.f;
    }

    #pragma unroll 4
    for (int ss = 0; ss < SS; ++ss) {
        const float  mv = Mb[(size_t)ss * DD + d];
        const float4 a4 = *(const float4*)&al4[ss][0];   // broadcast b128
        oacc[0] = fmaf((&a4.x)[0], mv, oacc[0]);
        oacc[1] = fmaf((&a4.x)[1], mv, oacc[1]);
        oacc[2] = fmaf((&a4.x)[2], mv, oacc[2]);
        oacc[3] = fmaf((&a4.x)[3], mv, oacc[3]);
    }

    #pragma unroll
    for (int t = 0; t < 4; ++t)
        out0[((size_t)((t0 + t) * BB) + b) * DD + d] = oacc[t] + pv[t];
}

// ---------------------------------------------------------------------------
extern "C" void kernel_launch(void* const* d_in, const int* in_sizes, int n_in,
                              void* d_out, int out_size, void* d_ws, size_t ws_size,
                              hipStream_t stream)
{
    const float* input = (const float*)d_in[0];
    const float* mbk   = (const float*)d_in[1];
    const int*   lens  = (const int*)d_in[2];
    const float* Wq    = (const float*)d_in[3];
    const float* bq    = (const float*)d_in[4];
    const float* Wc    = (const float*)d_in[5];
    const float* v     = (const float*)d_in[6];
    const float* Wout  = (const float*)d_in[7];
    const float* bout  = (const float*)d_in[8];

    float* out0 = (float*)d_out;               // [T,B,D] = 409600
    float* out1 = out0 + (size_t)BB * SS * DD; // [T,B,S] = 320000
    float* ws   = (float*)d_ws;
    unsigned short* x16 = (unsigned short*)(ws + XOFF);
    unsigned short* wt  = x16;                 // 2*1024*512 shorts
    unsigned short* ahi = x16 + 1048576;       // 2*800*512 shorts
    unsigned short* alo = ahi + 819200;

    hipLaunchKernelGGL(k0_all, dim3(1824), dim3(256), 0, stream,
                       Wq, Wc, Wout, input, mbk, wt, ahi, alo);
    hipLaunchKernelGGL(k1_mfma, dim3(25, 16, 2), dim3(64), 0, stream,
                       ahi, alo, wt, bq, bout, ws, out0);
    hipLaunchKernelGGL(k23_attn, dim3(100, 2), dim3(512), 0, stream,
                       ws, v, lens, out1, out0);
}

// Round 12
// 153.555 us; speedup vs baseline: 1.1178x; 1.1178x over previous
//
#include <hip/hip_runtime.h>
#include <math.h>

// Problem constants (reference: B=2, S=T=400, D=512)
#define BB 2
#define SS 400
#define DD 512
#define TWO_LOG2E 2.8853900817779268f

#if __has_builtin(__builtin_amdgcn_exp2f)
#define EXP2F(x) __builtin_amdgcn_exp2f(x)
#else
#define EXP2F(x) exp2f(x)
#endif
#define RCPF(x) __builtin_amdgcn_rcpf(x)

// Workspace float layout (peak 8.65 MB):
//   Ea   [0,       409600) : exp2(2L*(input@Wq + bq))            [B,T,D]
//   M    [409600,  819200) : mb@Wout_top                         [B,S,D]
//   Eb4  [819200, 1228800) : exp2(2L*(mb@Wc)), packed [B][D/4][S][4]
//   X    [1228800, ...)    : bf16 staging (shorts):
//        wt  [0,        1048576) : Wt [g][1024][512]
//        ahi [1048576,  1458176) : hi(A) [g][800][512]
//        alo [1458176,  1867776) : lo(A) [g][800][512]
// out0 gets input@Wout_bot + bout from k1 (g0 cols>=512); k3 atomically adds
// align@M (s-split x2, 3.3 MB atomic volume — R4-proven safe regime).
#define EAOFF 0
#define MOFF 409600
#define EB4OFF 819200
#define XOFF 1228800

typedef __bf16 bf16x8 __attribute__((ext_vector_type(8)));
typedef float floatx16 __attribute__((ext_vector_type(16)));

// ---------------------------------------------------------------------------
// K0: fused prep. Flat grid 1824 blocks, 256 thr.
//  gid < 1024: Wt[g][n][k] bf16 transpose-pack (32x32 LDS tiles).
//  gid >= 1024: two-term bf16 split of A (input / mb).
// ---------------------------------------------------------------------------
__global__ __launch_bounds__(256) void k0_all(
    const float* __restrict__ Wq, const float* __restrict__ Wc,
    const float* __restrict__ Wout, const float* __restrict__ input,
    const float* __restrict__ mbk, unsigned short* __restrict__ wt,
    unsigned short* __restrict__ ahi, unsigned short* __restrict__ alo)
{
    const int gid = blockIdx.x;
    if (gid < 1024) {
        const int g   = gid >> 9;
        const int rem = gid & 511;
        const int k0  = (rem & 15) * 32;
        const int n0  = (rem >> 4) * 32;

        __shared__ float tile[32][33];
        const int nn  = threadIdx.x & 31;
        const int kk0 = threadIdx.x >> 5;
        const int n   = n0 + nn;

        #pragma unroll
        for (int p = 0; p < 4; ++p) {
            const int k = k0 + kk0 + p * 8;
            float val;
            if (n0 < 512) val = (g ? Wc : Wq)[(size_t)k * 512 + n];
            else          val = Wout[((size_t)(g ? k : 512 + k)) * 512 + (n - 512)];
            tile[kk0 + p * 8][nn] = val;
        }
        __syncthreads();

        const int kc = threadIdx.x & 31;
        #pragma unroll
        for (int p = 0; p < 4; ++p) {
            const int nl = (threadIdx.x >> 5) + p * 8;
            const __bf16 h = (__bf16)tile[kc][nl];
            wt[((size_t)(g * 1024 + n0 + nl)) * 512 + k0 + kc] =
                __builtin_bit_cast(unsigned short, h);
        }
    } else {
        const int cid = gid - 1024;             // 0..799
        const int g   = (cid >= 400) ? 1 : 0;
        const int i4  = (cid - g * 400) * 256 + threadIdx.x;   // 0..102399
        const float4 a = ((const float4*)(g ? mbk : input))[i4];
        ushort4 h, l;
        #pragma unroll
        for (int j = 0; j < 4; ++j) {
            const float av = (&a.x)[j];
            const __bf16 hh = (__bf16)av;
            (&h.x)[j] = __builtin_bit_cast(unsigned short, hh);
            const __bf16 ll = (__bf16)(av - (float)hh);
            (&l.x)[j] = __builtin_bit_cast(unsigned short, ll);
        }
        ((ushort4*)(ahi + (size_t)g * 409600))[i4] = h;
        ((ushort4*)(alo + (size_t)g * 409600))[i4] = l;
    }
}

// ---------------------------------------------------------------------------
// K1: two merged GEMMs (800 x 1024 x 512) via MFMA, pre-split bf16 A.
// Grid (25 mtiles, 16 npairs, 2 g), 64 thr = 1 wave; wave tile 32x64.
// Inner loop: 4x 16B loads + 4 MFMA, zero VALU.
// C/D: col=lane&31, row=(reg&3)+8*(reg>>2)+4*(lane>>5).
// Fused epilogues by n-range/g: Ea, out0(=P+bout), Eb4 scatter, M.
// ---------------------------------------------------------------------------
__global__ __launch_bounds__(64) void k1_mfma(
    const unsigned short* __restrict__ ahi, const unsigned short* __restrict__ alo,
    const unsigned short* __restrict__ wt, const float* __restrict__ bq,
    const float* __restrict__ bout, float* __restrict__ ws,
    float* __restrict__ out0)
{
    const int lane = threadIdx.x;
    const int mt   = blockIdx.x;          // 0..24
    const int np   = blockIdx.y;          // 0..15
    const int g    = blockIdx.z;
    const int m    = lane & 31;
    const int kh   = lane >> 5;
    const int n0   = np * 64;

    const size_t arow = ((size_t)g * 800 + mt * 32 + m) * 512 + kh * 8;
    const unsigned short* __restrict__ ah = ahi + arow;
    const unsigned short* __restrict__ al = alo + arow;
    const unsigned short* __restrict__ w0 =
        wt + ((size_t)(g * 1024 + n0 + m)) * 512 + kh * 8;
    const unsigned short* __restrict__ w1 = w0 + (size_t)32 * 512;

    floatx16 acc0h, acc0l, acc1h, acc1l;
    #pragma unroll
    for (int i = 0; i < 16; ++i) { acc0h[i] = 0.f; acc0l[i] = 0.f;
                                   acc1h[i] = 0.f; acc1l[i] = 0.f; }

    #pragma unroll 4
    for (int ks = 0; ks < 32; ++ks) {
        const bf16x8 va0 = *(const bf16x8*)(ah + ks * 16);
        const bf16x8 va1 = *(const bf16x8*)(al + ks * 16);
        const bf16x8 bh0 = *(const bf16x8*)(w0 + ks * 16);
        const bf16x8 bh1 = *(const bf16x8*)(w1 + ks * 16);

        acc0h = __builtin_amdgcn_mfma_f32_32x32x16_bf16(va0, bh0, acc0h, 0, 0, 0);
        acc0l = __builtin_amdgcn_mfma_f32_32x32x16_bf16(va1, bh0, acc0l, 0, 0, 0);
        acc1h = __builtin_amdgcn_mfma_f32_32x32x16_bf16(va0, bh1, acc1h, 0, 0, 0);
        acc1l = __builtin_amdgcn_mfma_f32_32x32x16_bf16(va1, bh1, acc1l, 0, 0, 0);
    }

    const floatx16 c0 = acc0h + acc0l;
    const floatx16 c1 = acc1h + acc1l;
    const int rbase = kh * 4;

    #pragma unroll
    for (int r = 0; r < 16; ++r) {
        const int row  = (r & 3) + 8 * (r >> 2) + rbase;   // 0..31
        const int grow = mt * 32 + row;                    // 0..799
        const int bi   = (grow >= SS) ? 1 : 0;
        const int rl   = grow - bi * SS;                   // t or s local
        #pragma unroll
        for (int u = 0; u < 2; ++u) {
            const float val  = u ? c1[r] : c0[r];
            const int   gcol = n0 + u * 32 + m;
            if (g == 0) {
                if (gcol < 512) {
                    ws[EAOFF + (size_t)grow * 512 + gcol] =
                        EXP2F(TWO_LOG2E * (val + bq[gcol]));
                } else {
                    const int d = gcol - 512;
                    out0[((size_t)(rl * BB + bi)) * 512 + d] = val + bout[d];
                }
            } else {
                if (gcol < 512) {
                    ws[EB4OFF + (size_t)((bi * 128 + (gcol >> 2)) * SS + rl) * 4
                       + (gcol & 3)] = EXP2F(TWO_LOG2E * val);
                } else {
                    ws[MOFF + (size_t)grow * 512 + (gcol - 512)] = val;
                }
            }
        }
    }
}

// ---------------------------------------------------------------------------
// K2: fused scores + softmax. Block = (t-pair, b), grid (200,2)=400 blocks,
// 448 thr; thread = s. score(t,s) = -2 sum_e v_e/(Ea[t][e]*Eb[e][s]+1)
// (t-independent Sigma v dropped — cancels in softmax). Ea/v staged in LDS;
// Eb float4-packed coalesced. Softmax inline, align written to out1 [T,B,S].
// ---------------------------------------------------------------------------
__global__ __launch_bounds__(448) void k2_attn(
    const float* __restrict__ ws, const float* __restrict__ v,
    const int* __restrict__ lens, float* __restrict__ out1)
{
    const int tp = blockIdx.x;            // 0..199
    const int b  = blockIdx.y;
    const int t0 = tp * 2;
    const int t1 = t0 + 1;
    const int tid = threadIdx.x;
    const int s   = tid;
    const int sidx = (s < SS) ? s : 0;
    const int len  = lens[b];

    __shared__ float lea[2][512];
    __shared__ float lv[512];
    for (int i = tid; i < 1024; i += 448)
        lea[i >> 9][i & 511] =
            ws[EAOFF + (size_t)(b * SS + t0 + (i >> 9)) * 512 + (i & 511)];
    for (int i = tid; i < 512; i += 448) lv[i] = v[i];
    __syncthreads();

    const float4* __restrict__ eb4 =
        (const float4*)(ws + EB4OFF) + (size_t)b * 128 * SS + sidx;

    float acc0 = 0.f, acc1 = 0.f;
    #pragma unroll 4
    for (int e4 = 0; e4 < 128; ++e4) {
        const float4 eb  = eb4[(size_t)e4 * SS];
        const float4 vv  = *(const float4*)&lv[e4 * 4];
        const float4 ea0 = *(const float4*)&lea[0][e4 * 4];
        const float4 ea1 = *(const float4*)&lea[1][e4 * 4];
        #pragma unroll
        for (int j = 0; j < 4; ++j) {
            const float ebv = (&eb.x)[j];
            const float vj  = (&vv.x)[j];
            acc0 = fmaf(vj, RCPF(fmaf((&ea0.x)[j], ebv, 1.f)), acc0);
            acc1 = fmaf(vj, RCPF(fmaf((&ea1.x)[j], ebv, 1.f)), acc1);
        }
    }

    const bool v0 = (s < SS) && (s < len) && (s != t0);
    const bool v1 = (s < SS) && (s < len) && (s != t1);
    const float sc0 = v0 ? -2.f * acc0 : -INFINITY;
    const float sc1 = v1 ? -2.f * acc1 : -INFINITY;

    __shared__ float wred0[8], wred1[8];
    const int wid  = tid >> 6;
    const int lane = tid & 63;

    float m0 = sc0, m1 = sc1;
    #pragma unroll
    for (int off = 32; off > 0; off >>= 1) {
        m0 = fmaxf(m0, __shfl_xor(m0, off));
        m1 = fmaxf(m1, __shfl_xor(m1, off));
    }
    if (lane == 0) { wred0[wid] = m0; wred1[wid] = m1; }
    __syncthreads();
    float mx0 = wred0[0], mx1 = wred1[0];
    #pragma unroll
    for (int w = 1; w < 7; ++w) {
        mx0 = fmaxf(mx0, wred0[w]);
        mx1 = fmaxf(mx1, wred1[w]);
    }
    __syncthreads();

    const float p0 = v0 ? __expf(sc0 - mx0) : 0.f;
    const float p1 = v1 ? __expf(sc1 - mx1) : 0.f;
    float s0v = p0, s1v = p1;
    #pragma unroll
    for (int off = 32; off > 0; off >>= 1) {
        s0v += __shfl_xor(s0v, off);
        s1v += __shfl_xor(s1v, off);
    }
    if (lane == 0) { wred0[wid] = s0v; wred1[wid] = s1v; }
    __syncthreads();
    float tot0 = wred0[0], tot1 = wred1[0];
    #pragma unroll
    for (int w = 1; w < 7; ++w) { tot0 += wred0[w]; tot1 += wred1[w]; }
    const float inv0 = RCPF(tot0);
    const float inv1 = RCPF(tot1);

    if (s < SS) {
        out1[((size_t)(t0 * BB) + b) * SS + s] = p0 * inv0;
        out1[((size_t)(t1 * BB) + b) * SS + s] = p1 * inv1;
    }
}

// ---------------------------------------------------------------------------
// K3: out0[t,b,d] += sum_{s in half} align[t,b,s] * M[b,s,d].
// Grid (2 dhalf, 200 rowquads, 2 shalf) = 800 blocks (3.1 waves/SIMD),
// 256 thr; thread = 4 t-rows x 1 d col over 200 s. M L2-traffic unchanged
// (disjoint s-slabs). fp32 HW atomics onto P-initialized out0 (3.3 MB).
// ---------------------------------------------------------------------------
__global__ __launch_bounds__(256) void k3_out(
    const float* __restrict__ ws, const float* __restrict__ align_out,
    float* __restrict__ out0)
{
    const int d     = blockIdx.x * 256 + threadIdx.x;
    const int r0    = blockIdx.y * 4;
    const int s0    = blockIdx.z * 200;
    const int b     = (r0 >= SS) ? 1 : 0;
    const int tbase = r0 - b * SS;

    const float* __restrict__ Mb = ws + MOFF + (size_t)b * SS * DD;

    float acc[4];
    #pragma unroll
    for (int j = 0; j < 4; ++j) acc[j] = 0.f;

    float mA[4], mB[4];
    float4 alA[4], alB[4];

    auto LOAD = [&](float (&mm)[4], float4 (&al)[4], int s) {
        #pragma unroll
        for (int i = 0; i < 4; ++i)
            mm[i] = Mb[(size_t)(s + i) * DD + d];
        #pragma unroll
        for (int j = 0; j < 4; ++j)
            al[j] = *(const float4*)(align_out +
                     ((size_t)((tbase + j) * BB) + b) * SS + s);
    };
    auto FMA4 = [&](const float (&mm)[4], const float4 (&al)[4]) {
        #pragma unroll
        for (int j = 0; j < 4; ++j) {
            acc[j] = fmaf(al[j].x, mm[0], acc[j]);
            acc[j] = fmaf(al[j].y, mm[1], acc[j]);
            acc[j] = fmaf(al[j].z, mm[2], acc[j]);
            acc[j] = fmaf(al[j].w, mm[3], acc[j]);
        }
    };

    LOAD(mA, alA, s0);
    for (int s = s0; s < s0 + 200; s += 8) {
        LOAD(mB, alB, s + 4);
        FMA4(mA, alA);
        if (s + 8 < s0 + 200) LOAD(mA, alA, s + 8);
        FMA4(mB, alB);
    }

    #pragma unroll
    for (int j = 0; j < 4; ++j)
        unsafeAtomicAdd(&out0[((size_t)((tbase + j) * BB) + b) * DD + d], acc[j]);
}

// ---------------------------------------------------------------------------
extern "C" void kernel_launch(void* const* d_in, const int* in_sizes, int n_in,
                              void* d_out, int out_size, void* d_ws, size_t ws_size,
                              hipStream_t stream)
{
    const float* input = (const float*)d_in[0];
    const float* mbk   = (const float*)d_in[1];
    const int*   lens  = (const int*)d_in[2];
    const float* Wq    = (const float*)d_in[3];
    const float* bq    = (const float*)d_in[4];
    const float* Wc    = (const float*)d_in[5];
    const float* v     = (const float*)d_in[6];
    const float* Wout  = (const float*)d_in[7];
    const float* bout  = (const float*)d_in[8];

    float* out0 = (float*)d_out;               // [T,B,D] = 409600
    float* out1 = out0 + (size_t)BB * SS * DD; // [T,B,S] = 320000
    float* ws   = (float*)d_ws;
    unsigned short* x16 = (unsigned short*)(ws + XOFF);
    unsigned short* wt  = x16;                 // 2*1024*512 shorts
    unsigned short* ahi = x16 + 1048576;       // 2*800*512 shorts
    unsigned short* alo = ahi + 819200;

    hipLaunchKernelGGL(k0_all, dim3(1824), dim3(256), 0, stream,
                       Wq, Wc, Wout, input, mbk, wt, ahi, alo);
    hipLaunchKernelGGL(k1_mfma, dim3(25, 16, 2), dim3(64), 0, stream,
                       ahi, alo, wt, bq, bout, ws, out0);
    hipLaunchKernelGGL(k2_attn, dim3(200, 2), dim3(448), 0, stream,
                       ws, v, lens, out1);
    hipLaunchKernelGGL(k3_out, dim3(2, 200, 2), dim3(256), 0, stream,
                       ws, out1, out0);
}